// Round 3
// baseline (664.295 us; speedup 1.0000x reference)
//
#include <hip/hip_runtime.h>
#include <hip/hip_bf16.h>

// Problem constants (reference: WORLD_SIZE=8, M_LOCAL=1024, K=4096, N=4096)
#define M_TOTAL 8192
#define KDIM    4096
#define NDIM    4096

#define TM 128
#define TN 128
#define BK 32

typedef __bf16 bf16x8 __attribute__((ext_vector_type(8)));
typedef float  f32x4  __attribute__((ext_vector_type(4)));

// ---------------------------------------------------------------------------
// fp32 -> bf16 (RNE) convert. Lane-contiguous: each thread converts ONE
// float4 (16B load across lanes = 1KiB/wave/instr) -> uint2 bf16 store
// (512B/wave/instr). Grid-stride over concatenated A||W element range.
// ---------------------------------------------------------------------------
__device__ __forceinline__ unsigned short f32_to_bf16_rne(unsigned u) {
    unsigned r = u + 0x7fffu + ((u >> 16) & 1u);
    return (unsigned short)(r >> 16);
}

__global__ __launch_bounds__(256) void cvt_both(const float* __restrict__ A,
                                                unsigned short* __restrict__ Abf,
                                                long nA4,      // nA/4
                                                const float* __restrict__ W,
                                                unsigned short* __restrict__ Wbf,
                                                long nTot4) {  // (nA+nW)/4
    const long stride = (long)gridDim.x * 256;
    for (long i = (long)blockIdx.x * 256 + threadIdx.x; i < nTot4; i += stride) {
        const float* s;
        unsigned short* d;
        if (i < nA4) { s = A + i * 4;           d = Abf + i * 4; }
        else         { s = W + (i - nA4) * 4;   d = Wbf + (i - nA4) * 4; }
        uint4 x = *(const uint4*)s;
        uint2 o;
        o.x = (unsigned)f32_to_bf16_rne(x.x) | ((unsigned)f32_to_bf16_rne(x.y) << 16);
        o.y = (unsigned)f32_to_bf16_rne(x.z) | ((unsigned)f32_to_bf16_rne(x.w) << 16);
        *(uint2*)d = o;
    }
}

// ---------------------------------------------------------------------------
// async global -> LDS, 16B per lane (wave-uniform LDS base + lane*16)
// ---------------------------------------------------------------------------
__device__ __forceinline__ void gload_lds16(const unsigned short* g, unsigned short* l) {
    __builtin_amdgcn_global_load_lds(
        (const __attribute__((address_space(1))) unsigned int*)g,
        (__attribute__((address_space(3))) unsigned int*)l,
        16, 0, 0);
}

// ---------------------------------------------------------------------------
// C[M,N] = A[M,K] * B[N,K]^T   (bf16 inputs, fp32 out)
// 128x128 tile, BK=32, 256 threads (4 waves, 2x2), 16x16x32 bf16 MFMA.
// XOR K-chunk swizzle keeps LDS reads conflict-free (verified R2: conflicts=0).
// ---------------------------------------------------------------------------
__global__ __launch_bounds__(256) void gemm_bt(const unsigned short* __restrict__ A,
                                               const unsigned short* __restrict__ B,
                                               float* __restrict__ C) {
    __shared__ unsigned short lA[TM * BK];   // [128][32] shorts, 8 KiB
    __shared__ unsigned short lB[TN * BK];   // [128][32] shorts, 8 KiB

    const int tid  = threadIdx.x;
    const int wave = tid >> 6;
    const int lane = tid & 63;

    const int n0 = blockIdx.x * TN;
    const int m0 = blockIdx.y * TM;

    const int row_ic = lane >> 2;                                  // 0..15
    const int kchunk = (lane & 3) ^ ((lane >> 3) & 3);             // swizzled src chunk
    const int k_ic   = kchunk * 8;                                 // element offset

    const int c0 = wave;
    const int c1 = wave + 4;

    const unsigned short* gA0 = A + (size_t)(m0 + c0 * 16 + row_ic) * KDIM + k_ic;
    const unsigned short* gA1 = A + (size_t)(m0 + c1 * 16 + row_ic) * KDIM + k_ic;
    const unsigned short* gB0 = B + (size_t)(n0 + c0 * 16 + row_ic) * KDIM + k_ic;
    const unsigned short* gB1 = B + (size_t)(n0 + c1 * 16 + row_ic) * KDIM + k_ic;
    unsigned short* lA0 = &lA[c0 * 16 * BK];   // wave-uniform LDS bases
    unsigned short* lA1 = &lA[c1 * 16 * BK];
    unsigned short* lB0 = &lB[c0 * 16 * BK];
    unsigned short* lB1 = &lB[c1 * 16 * BK];

    // wave -> 64x64 quadrant; MFMA fragment indices
    const int wm   = wave & 1;
    const int wn   = wave >> 1;
    const int quad = lane >> 4;    // 0..3  (K-chunk index for A/B operands)
    const int r    = lane & 15;    // m (A) / n (B) / col (C)

    const int sidx = (quad ^ ((r >> 1) & 3)) * 8;   // swizzled read offset (elems)

    f32x4 acc[4][4] = {};

    for (int k0 = 0; k0 < KDIM; k0 += BK) {
        gload_lds16(gA0 + k0, lA0);
        gload_lds16(gA1 + k0, lA1);
        gload_lds16(gB0 + k0, lB0);
        gload_lds16(gB1 + k0, lB1);
        __syncthreads();   // drains vmcnt -> staged data visible

        bf16x8 aF[4], bF[4];
#pragma unroll
        for (int mi = 0; mi < 4; ++mi)
            aF[mi] = *(const bf16x8*)&lA[(wm * 64 + mi * 16 + r) * BK + sidx];
#pragma unroll
        for (int ni = 0; ni < 4; ++ni)
            bF[ni] = *(const bf16x8*)&lB[(wn * 64 + ni * 16 + r) * BK + sidx];

#pragma unroll
        for (int mi = 0; mi < 4; ++mi)
#pragma unroll
            for (int ni = 0; ni < 4; ++ni)
                acc[mi][ni] = __builtin_amdgcn_mfma_f32_16x16x32_bf16(
                    aF[mi], bF[ni], acc[mi][ni], 0, 0, 0);

        __syncthreads();   // all reads done before next stage overwrites
    }

    // epilogue: C/D layout col = lane&15, row = quad*4 + reg  [verified m89/m91]
#pragma unroll
    for (int mi = 0; mi < 4; ++mi) {
        const int row = m0 + wm * 64 + mi * 16 + quad * 4;
#pragma unroll
        for (int ni = 0; ni < 4; ++ni) {
            const int col = n0 + wn * 64 + ni * 16 + r;
            float* p = C + (size_t)row * NDIM + col;
#pragma unroll
            for (int rr = 0; rr < 4; ++rr)
                p[(size_t)rr * NDIM] = acc[mi][ni][rr];
        }
    }
}

// ---------------------------------------------------------------------------
extern "C" void kernel_launch(void* const* d_in, const int* in_sizes, int n_in,
                              void* d_out, int out_size, void* d_ws, size_t ws_size,
                              hipStream_t stream) {
    const float* A = (const float*)d_in[0];   // [8,1024,4096] == [8192,4096]
    const float* W = (const float*)d_in[1];   // [4096,4096]  (N,K)
    float* out = (float*)d_out;               // [8192,4096] fp32

    unsigned short* Abf = (unsigned short*)d_ws;                       // 64 MiB
    unsigned short* Wbf = Abf + (size_t)M_TOTAL * KDIM;                // 32 MiB

    const long nA = (long)M_TOTAL * KDIM;     // 33,554,432
    const long nW = (long)NDIM * KDIM;        // 16,777,216
    const long nA4   = nA / 4;
    const long nTot4 = (nA + nW) / 4;

    cvt_both<<<3072, 256, 0, stream>>>(A, Abf, nA4, W, Wbf, nTot4);

    dim3 grid(NDIM / TN, M_TOTAL / TM);       // (32, 64) = 2048 blocks
    gemm_bt<<<grid, 256, 0, stream>>>(Abf, Wbf, out);
}